// Round 5
// baseline (247.263 us; speedup 1.0000x reference)
//
#include <hip/hip_runtime.h>

// Problem constants
#define NB 2
#define LL 2048
#define DD 1024
#define HH 16
#define NHH (NB*HH)          // 32 (n,h) pairs
#define LT (LL/64)           // 32 tiles of 64
#define KT16 (LL/16)         // 128 16-col tiles
#define CEXP 0.0450842200277801f   // log2(e)/32 : exp(x/32) == exp2(x*CEXP)

typedef __bf16 bf16x8 __attribute__((ext_vector_type(8)));
typedef unsigned short u16x8 __attribute__((ext_vector_type(8)));
typedef float f32x4 __attribute__((ext_vector_type(4)));

#define MFMA16 __builtin_amdgcn_mfma_f32_16x16x32_bf16
#define EXP2 __builtin_amdgcn_exp2f

__device__ __forceinline__ unsigned short f2bf(float f) {
    unsigned u = __float_as_uint(f);
    return (unsigned short)((u + 0x7fffu + ((u >> 16) & 1u)) >> 16);   // RNE
}
__device__ __forceinline__ float bf2f(unsigned short u) {
    return __uint_as_float(((unsigned)u) << 16);
}
__device__ __forceinline__ bf16x8 ldfrag(const unsigned short* p) {
    return *reinterpret_cast<const bf16x8*>(p);
}
__device__ __forceinline__ bf16x8 cvt8v(float4 a, float4 b) {
    u16x8 u;
    u[0]=f2bf(a.x); u[1]=f2bf(a.y); u[2]=f2bf(a.z); u[3]=f2bf(a.w);
    u[4]=f2bf(b.x); u[5]=f2bf(b.y); u[6]=f2bf(b.z); u[7]=f2bf(b.w);
    return __builtin_bit_cast(bf16x8, u);
}
__device__ __forceinline__ ushort4 pack4(f32x4 d, float sc) {
    ushort4 o;
    o.x = f2bf(d[0]*sc); o.y = f2bf(d[1]*sc); o.z = f2bf(d[2]*sc); o.w = f2bf(d[3]*sc);
    return o;
}
// async global->LDS, 16B per lane; LDS dest must be linear (base + lane*16)
__device__ __forceinline__ void gload16(const unsigned short* g, unsigned short* l) {
    __builtin_amdgcn_global_load_lds(
        (const __attribute__((address_space(1))) unsigned int*)g,
        (__attribute__((address_space(3))) unsigned int*)l, 16, 0, 0);
}

// ---------------------------------------------------------------------------
// K0 (prep): merged wcvt (6 blocks) + fcw cvt (1024 blocks) + zero of the
// two atomic accumulators -> one launch.
// ---------------------------------------------------------------------------
__global__ __launch_bounds__(256) void prep_kernel(
    const float* __restrict__ Wk, const float* __restrict__ Wq,
    const float* __restrict__ Wv, unsigned short* __restrict__ wfrag,
    const float* __restrict__ fc_w, unsigned short* __restrict__ fcwb,
    float* __restrict__ zreg)
{
    const int bid = blockIdx.x;
    const int t = threadIdx.x;
    if (bid < 6) {
        // wcvt: Wk,Wq,Wv -> bf16 MFMA A-frags, proj's per-lane layout
        const int s = bid * 256 + t;   // 0..1535
        const int m = s >> 9;
        const int rem = s & 511;
        const int f = rem >> 6;
        const int lane = rem & 63;
        const int n16 = lane & 15, quad = lane >> 4;
        const int mt = f >> 1, half = f & 1;
        const float* W = (m == 0) ? Wk : (m == 1) ? Wq : Wv;
        const float* p = W + (mt*16 + n16)*64 + quad*8 + half*32;
        float4 a = *reinterpret_cast<const float4*>(p);
        float4 b = *reinterpret_cast<const float4*>(p + 4);
        *reinterpret_cast<bf16x8*>(wfrag + (size_t)s * 8) = cvt8v(a, b);
    } else if (bid < 6 + 1024) {
        // fcw: fc_w fp32 -> bf16
        const int idx = (bid - 6) * 1024 + t * 4;
        float4 wv = *reinterpret_cast<const float4*>(fc_w + idx);
        ushort4 o;
        o.x = f2bf(wv.x); o.y = f2bf(wv.y); o.z = f2bf(wv.z); o.w = f2bf(wv.w);
        *reinterpret_cast<ushort4*>(fcwb + idx) = o;
    } else {
        // zero Zbuf + colsum (adjacent, 131072 floats)
        const int i = (bid - 1030) * 1024 + t * 4;
        *reinterpret_cast<float4*>(zreg + i) = (float4){0.f, 0.f, 0.f, 0.f};
    }
}

// ---------------------------------------------------------------------------
// K1: projections via MFMA, D = W(A) . X^T(B); C/D lane layout gives each
// lane 4 consecutive d for one row l -> 8B packed stores. Grid (64,16,2)
// [REVERTED from h-pair: the h-pair variant regressed (43.5 vs 40.7 cold);
// warm instances are below the profiling cutoff -- proj was cold-start
// dominated, not MLP-starved].
// z=0: keys/query/okeys (Wk,Wq) + ediag; z=1: values/ovals (Wv).
// ---------------------------------------------------------------------------
__global__ __launch_bounds__(256) void proj_kernel(
    const float* __restrict__ values, const float* __restrict__ keys,
    const float* __restrict__ query,  const float* __restrict__ ovals,
    const float* __restrict__ okeys,  const unsigned short* __restrict__ wfrag,
    unsigned short* __restrict__ qb, unsigned short* __restrict__ okb,
    unsigned short* __restrict__ vb, unsigned short* __restrict__ ovb,
    float* __restrict__ ediag)
{
    const int t = threadIdx.x;
    const int w = t >> 6;
    const int lane = t & 63;
    const int n16 = lane & 15;
    const int quad = lane >> 4;
    const int h = blockIdx.y;
    const int row = blockIdx.x * 64 + w * 16 + n16;  // (n*L+l) == this lane's C-col
    const int nn = row >> 11;
    const int ll = row & 2047;
    const size_t xoff  = (size_t)row * DD + h * 64 + quad * 8;       // B-frag src
    const size_t qbase = (((size_t)(nn * HH + h)) * LL + ll) * 64;   // [nh][l][64]
    const size_t vbase = (size_t)row * DD + h * 64;                  // [row][1024]

    if (blockIdx.z == 0) {
        // ---- issue ALL loads first (independent) ----
        const float4* kp = reinterpret_cast<const float4*>(keys  + xoff);
        const float4* qp = reinterpret_cast<const float4*>(query + xoff);
        const float4* op = reinterpret_cast<const float4*>(okeys + xoff);
        float4 k0 = kp[0], k1 = kp[1], k2 = kp[8], k3 = kp[9];   // +0,+4,+32,+36
        float4 q0 = qp[0], q1 = qp[1], q2 = qp[8], q3 = qp[9];
        float4 o0 = op[0], o1 = op[1], o2 = op[8], o3 = op[9];
        bf16x8 wk[8], wq[8];
#pragma unroll
        for (int f = 0; f < 8; ++f) {
            wk[f] = ldfrag(wfrag + (size_t)(f * 64 + lane) * 8);
            wq[f] = ldfrag(wfrag + (size_t)((8 + f) * 64 + lane) * 8);
        }
        // ---- convert ----
        bf16x8 xk0 = cvt8v(k0, k1), xk1 = cvt8v(k2, k3);
        bf16x8 xq0 = cvt8v(q0, q1), xq1 = cvt8v(q2, q3);
        bf16x8 xo0 = cvt8v(o0, o1), xo1 = cvt8v(o2, o3);
        // ---- MFMA ----
        f32x4 ka[4], qa[4];
#pragma unroll
        for (int mt = 0; mt < 4; ++mt) {
            f32x4 d = {0.f,0.f,0.f,0.f};
            d = MFMA16(wk[mt*2], xk0, d, 0,0,0);
            ka[mt] = MFMA16(wk[mt*2+1], xk1, d, 0,0,0);
        }
#pragma unroll
        for (int mt = 0; mt < 4; ++mt) {
            f32x4 d = {0.f,0.f,0.f,0.f};
            d = MFMA16(wq[mt*2], xq0, d, 0,0,0);
            qa[mt] = MFMA16(wq[mt*2+1], xq1, d, 0,0,0);
            *reinterpret_cast<ushort4*>(qb + qbase + mt*16 + quad*4) = pack4(qa[mt], CEXP);
        }
#pragma unroll
        for (int mt = 0; mt < 4; ++mt) {
            f32x4 d = {0.f,0.f,0.f,0.f};
            d = MFMA16(wk[mt*2], xo0, d, 0,0,0);
            d = MFMA16(wk[mt*2+1], xo1, d, 0,0,0);
            *reinterpret_cast<ushort4*>(okb + qbase + mt*16 + quad*4) = pack4(d, 1.0f);
        }
        // ediag[l] = sum_d q*k (fp32)
        float p = 0.f;
#pragma unroll
        for (int mt = 0; mt < 4; ++mt)
            p += qa[mt][0]*ka[mt][0] + qa[mt][1]*ka[mt][1]
               + qa[mt][2]*ka[mt][2] + qa[mt][3]*ka[mt][3];
        p += __shfl_xor(p, 16);
        p += __shfl_xor(p, 32);
        if (lane < 16)
            ediag[((size_t)(nn * HH + h)) * LL + ll] = p;
    } else {
        const float4* vp = reinterpret_cast<const float4*>(values + xoff);
        const float4* op = reinterpret_cast<const float4*>(ovals  + xoff);
        float4 v0 = vp[0], v1 = vp[1], v2 = vp[8], v3 = vp[9];
        float4 o0 = op[0], o1 = op[1], o2 = op[8], o3 = op[9];
        bf16x8 wv[8];
#pragma unroll
        for (int f = 0; f < 8; ++f)
            wv[f] = ldfrag(wfrag + (size_t)((16 + f) * 64 + lane) * 8);
        bf16x8 xv0 = cvt8v(v0, v1), xv1 = cvt8v(v2, v3);
        bf16x8 xo0 = cvt8v(o0, o1), xo1 = cvt8v(o2, o3);
#pragma unroll
        for (int mt = 0; mt < 4; ++mt) {
            f32x4 d = {0.f,0.f,0.f,0.f};
            d = MFMA16(wv[mt*2], xv0, d, 0,0,0);
            d = MFMA16(wv[mt*2+1], xv1, d, 0,0,0);
            *reinterpret_cast<ushort4*>(vb + vbase + mt*16 + quad*4) = pack4(d, 1.0f);
        }
#pragma unroll
        for (int mt = 0; mt < 4; ++mt) {
            f32x4 d = {0.f,0.f,0.f,0.f};
            d = MFMA16(wv[mt*2], xo0, d, 0,0,0);
            d = MFMA16(wv[mt*2+1], xo1, d, 0,0,0);
            *reinterpret_cast<ushort4*>(ovb + vbase + mt*16 + quad*4) = pack4(d, 1.0f);
        }
    }
}

// ---------------------------------------------------------------------------
// K2: partial row-sums of exp(E/32) via MFMA, swapped operands (E^T tiles).
// XCD-PINNED grid: 1D 1024 blocks; xcd = bid&7, nh = xcd*4 + ((bid>>3)>>5),
// px = (bid>>3)&31. All 32 worker-blocks of one nh land on ONE XCD, so that
// nh's qb+okb slice (1 MB; 4 nh x 1 MB = 4 MB = private L2) stays L2-hot --
// the ~135 MB of logical tile re-reads were previously cross-XCD L3 traffic
// (~3.3 TB/s sustained; the measured stall).
// ---------------------------------------------------------------------------
__global__ __launch_bounds__(256) void zrow_part(
    const unsigned short* __restrict__ qb, const unsigned short* __restrict__ okb,
    float* __restrict__ Zbuf)
{
    const int bid = blockIdx.x;       // 0..1023
    const int xcd = bid & 7;
    const int slot = bid >> 3;        // 0..127
    const int nh = xcd * 4 + (slot >> 5);
    const int px = slot & 31;
    const int pair = px >> 1;         // 0..15
    const int s = px & 1;
    const int t = threadIdx.x;
    const int w = t >> 6;
    const int lane = t & 63;
    const int n = lane & 15;
    const int quad = lane >> 4;
    const size_t base = (size_t)nh * (LL * 64);
    const size_t nhL = (size_t)nh * LL;
    const int r0 = 4 * s + w;     // l-tile residue 0..7, stride 8

#pragma unroll
    for (int half = 0; half < 2; ++half) {
        const int qt = half ? (31 - pair) : pair;
        const int kend = 4 * qt + 4;

        // B-frags: qb rows q = qt*64 + ct*16 + n (q on lanes)
        bf16x8 bq[4][2];
#pragma unroll
        for (int ct = 0; ct < 4; ++ct) {
            const unsigned short* p = qb + base + (size_t)(qt*64 + ct*16 + n) * 64 + quad * 8;
            bq[ct][0] = ldfrag(p); bq[ct][1] = ldfrag(p + 32);
        }

        float zacc[4] = {0.f, 0.f, 0.f, 0.f};

        // 3-deep prefetch of streamed okb l-tiles
        bf16x8 a0A = {}, a1A = {}, a0B = {}, a1B = {}, a0C = {}, a1C = {};
        if (r0 < kend) {
            const unsigned short* p = okb + base + (size_t)(r0*16 + n) * 64 + quad * 8;
            a0A = ldfrag(p); a1A = ldfrag(p + 32);
        }
        if (r0 + 8 < kend) {
            const unsigned short* p = okb + base + (size_t)((r0+8)*16 + n) * 64 + quad * 8;
            a0B = ldfrag(p); a1B = ldfrag(p + 32);
        }
        if (r0 + 16 < kend) {
            const unsigned short* p = okb + base + (size_t)((r0+16)*16 + n) * 64 + quad * 8;
            a0C = ldfrag(p); a1C = ldfrag(p + 32);
        }
        for (int kt = r0; kt < kend; kt += 8) {
            bf16x8 a0 = a0A, a1 = a1A;
            a0A = a0B; a1A = a1B; a0B = a0C; a1B = a1C;
            if (kt + 24 < kend) {
                const unsigned short* p = okb + base + (size_t)((kt+24)*16 + n) * 64 + quad * 8;
                a0C = ldfrag(p); a1C = ldfrag(p + 32);
            }
            const int dk = kt - 4*qt;   // ct<dk empty, ct==dk diag, ct>dk full
#pragma unroll
            for (int ct = 0; ct < 4; ++ct) {
                if (ct < dk) continue;
                f32x4 d = {0.f,0.f,0.f,0.f};
                d = MFMA16(a0, bq[ct][0], d, 0,0,0);
                d = MFMA16(a1, bq[ct][1], d, 0,0,0);
                if (ct == dk) {                            // diagonal tile: l<q only
#pragma unroll
                    for (int r = 0; r < 4; ++r)
                        if (quad*4 + r < n) zacc[ct] += EXP2(d[r]);
                } else {
#pragma unroll
                    for (int r = 0; r < 4; ++r) zacc[ct] += EXP2(d[r]);
                }
            }
        }

        // tail: reduce across quads, atomic from 16 lanes per sub-tile
#pragma unroll
        for (int ct = 0; ct < 4; ++ct) {
            float z = zacc[ct];
            z += __shfl_down(z, 32);
            z += __shfl_down(z, 16);
            if (lane < 16)
                atomicAdd(&Zbuf[nhL + qt*64 + ct*16 + lane], z);
        }
    }
}

// ---------------------------------------------------------------------------
// K3: partial colsum[l] = sum_{q>l} exp(e[q,l]/32)*invZ[q].
// invZ computed inline from Zbuf+ediag. XCD-pinned grid like zrow.
// ---------------------------------------------------------------------------
__global__ __launch_bounds__(256) void colsum_part(
    const unsigned short* __restrict__ qb, const unsigned short* __restrict__ okb,
    const float* __restrict__ Zbuf, const float* __restrict__ ediag,
    float* __restrict__ colsum)
{
    const int bid = blockIdx.x;       // 0..1023
    const int xcd = bid & 7;
    const int slot = bid >> 3;        // 0..127
    const int nh = xcd * 4 + (slot >> 5);
    const int px = slot & 31;
    const int pair = px >> 1;         // 0..15
    const int s = px & 1;
    const int t = threadIdx.x;
    const int w = t >> 6;
    const int lane = t & 63;
    const int n = lane & 15;
    const int quad = lane >> 4;
    const size_t base = (size_t)nh * (LL * 64);
    const size_t nhL = (size_t)nh * LL;
    const int r0 = 4 * s + w;     // q-tile residue 0..7, stride 8

#pragma unroll
    for (int half = 0; half < 2; ++half) {
        const int lt = half ? (31 - pair) : pair;

        bf16x8 bl[4][2];
#pragma unroll
        for (int ct = 0; ct < 4; ++ct) {
            const unsigned short* p = okb + base + (size_t)(lt*64 + ct*16 + n) * 64 + quad * 8;
            bl[ct][0] = ldfrag(p); bl[ct][1] = ldfrag(p + 32);
        }

        float cacc[4] = {0.f, 0.f, 0.f, 0.f};

        const int kstart = 4*lt + r0;
        // 3-deep prefetch of streamed qb q-tiles + their Zbuf/ediag float4s
        bf16x8 a0A = {}, a1A = {}, a0B = {}, a1B = {}, a0C = {}, a1C = {};
        float4 zA = {0,0,0,0}, zB = {0,0,0,0}, zC = {0,0,0,0};
        float4 eA = {0,0,0,0}, eB = {0,0,0,0}, eC = {0,0,0,0};
        if (kstart < KT16) {
            const unsigned short* p = qb + base + (size_t)(kstart*16 + n) * 64 + quad * 8;
            a0A = ldfrag(p); a1A = ldfrag(p + 32);
            zA = *reinterpret_cast<const float4*>(Zbuf  + nhL + kstart*16 + quad*4);
            eA = *reinterpret_cast<const float4*>(ediag + nhL + kstart*16 + quad*4);
        }
        if (kstart + 8 < KT16) {
            const unsigned short* p = qb + base + (size_t)((kstart+8)*16 + n) * 64 + quad * 8;
            a0B = ldfrag(p); a1B = ldfrag(p + 32);
            zB = *reinterpret_cast<const float4*>(Zbuf  + nhL + (kstart+8)*16 + quad*4);
            eB = *reinterpret_cast<const float4*>(ediag + nhL + (kstart+8)*16 + quad*4);
        }
        if (kstart + 16 < KT16) {
            const unsigned short* p = qb + base + (size_t)((kstart+16)*16 + n) * 64 + quad * 8;
            a0C = ldfrag(p); a1C = ldfrag(p + 32);
            zC = *reinterpret_cast<const float4*>(Zbuf  + nhL + (kstart+16)*16 + quad*4);
            eC = *reinterpret_cast<const float4*>(ediag + nhL + (kstart+16)*16 + quad*4);
        }
        for (int kt = kstart; kt < KT16; kt += 8) {
            bf16x8 a0 = a0A, a1 = a1A; const float4 zv = zA, ev = eA;
            a0A = a0B; a1A = a1B; zA = zB; eA = eB;
            a0B = a0C; a1B = a1C; zB = zC; eB = eC;
            if (kt + 24 < KT16) {
                const unsigned short* p = qb + base + (size_t)((kt+24)*16 + n) * 64 + quad * 8;
                a0C = ldfrag(p); a1C = ldfrag(p + 32);
                zC = *reinterpret_cast<const float4*>(Zbuf  + nhL + (kt+24)*16 + quad*4);
                eC = *reinterpret_cast<const float4*>(ediag + nhL + (kt+24)*16 + quad*4);
            }
            // inline zfin: iz = 1/(Z + exp2(e*CEXP))
            float4 izv;
            izv.x = 1.f / (zv.x + EXP2(ev.x * CEXP));
            izv.y = 1.f / (zv.y + EXP2(ev.y * CEXP));
            izv.z = 1.f / (zv.z + EXP2(ev.z * CEXP));
            izv.w = 1.f / (zv.w + EXP2(ev.w * CEXP));
            const int dk = kt - 4*lt;   // ct>dk empty, ct==dk diag, ct<dk full
#pragma unroll
            for (int ct = 0; ct < 4; ++ct) {
                if (ct > dk) continue;
                f32x4 d = {0.f,0.f,0.f,0.f};
                d = MFMA16(a0, bl[ct][0], d, 0,0,0);
                d = MFMA16(a1, bl[ct][1], d, 0,0,0);
                if (ct == dk) {                            // diagonal tile: q>l only
                    if (quad*4 + 0 > n) cacc[ct] += EXP2(d[0]) * izv.x;
                    if (quad*4 + 1 > n) cacc[ct] += EXP2(d[1]) * izv.y;
                    if (quad*4 + 2 > n) cacc[ct] += EXP2(d[2]) * izv.z;
                    if (quad*4 + 3 > n) cacc[ct] += EXP2(d[3]) * izv.w;
                } else {
                    cacc[ct] += EXP2(d[0]) * izv.x;
                    cacc[ct] += EXP2(d[1]) * izv.y;
                    cacc[ct] += EXP2(d[2]) * izv.z;
                    cacc[ct] += EXP2(d[3]) * izv.w;
                }
            }
        }

#pragma unroll
        for (int ct = 0; ct < 4; ++ct) {
            float c = cacc[ct];
            c += __shfl_down(c, 32);
            c += __shfl_down(c, 16);
            if (lane < 16)
                atomicAdd(&colsum[nhL + lt*64 + ct*16 + lane], c);
        }
    }
}

// ---------------------------------------------------------------------------
// K6: out = (diag_s*vb + colsum*ovb) @ fcwb^T + fc_b  -- att fused into the
// GEMM's A-staging; diag_s computed inline from Zbuf+ediag.
// ---------------------------------------------------------------------------
#define LOADA(vS, ovS, zS, eS, csS, k) do {                                \
    vS  = ldfrag(pv  + (k)*32);                                            \
    ovS = ldfrag(pov + (k)*32);                                            \
    zS  = Zbuf  [scbase + ((k)>>1)*LL];                                    \
    eS  = ediag [scbase + ((k)>>1)*LL];                                    \
    csS = colsum[scbase + ((k)>>1)*LL];                                    \
} while (0)

#define CVTWRITE(vS, ovS, zS, eS, csS, dst) do {                           \
    const float de_ = EXP2(eS * CEXP);                                     \
    const float ds_ = de_ * (1.f / (zS + de_));                            \
    u16x8 vu_ = __builtin_bit_cast(u16x8, vS);                             \
    u16x8 ou_ = __builtin_bit_cast(u16x8, ovS);                            \
    u16x8 o_;                                                              \
    _Pragma("unroll")                                                      \
    for (int i_ = 0; i_ < 8; ++i_)                                         \
        o_[i_] = f2bf(ds_ * bf2f(vu_[i_]) + csS * bf2f(ou_[i_]));          \
    *reinterpret_cast<u16x8*>(dst) = o_;                                   \
} while (0)

#define COMPUTE(Abuf, Bbuf) do {                                           \
    bf16x8 af_[4], bf_[2];                                                 \
    _Pragma("unroll")                                                      \
    for (int mt = 0; mt < 4; ++mt)                                         \
        af_[mt] = ldfrag((Abuf) + (wr*64 + mt*16 + n)*32 + quad*8);        \
    _Pragma("unroll")                                                      \
    for (int nt = 0; nt < 2; ++nt)                                         \
        bf_[nt] = ldfrag((Bbuf) + (wc*32 + nt*16 + n)*32 + quad*8);        \
    _Pragma("unroll")                                                      \
    for (int mt = 0; mt < 4; ++mt)                                         \
        _Pragma("unroll")                                                  \
        for (int nt = 0; nt < 2; ++nt)                                     \
            acc[mt][nt] = MFMA16(af_[mt], bf_[nt], acc[mt][nt], 0,0,0);    \
} while (0)

__global__ __launch_bounds__(512) void out_kernel(
    const unsigned short* __restrict__ vb, const unsigned short* __restrict__ ovb,
    const float* __restrict__ Zbuf, const float* __restrict__ ediag,
    const float* __restrict__ colsum,
    const unsigned short* __restrict__ fcwb, const float* __restrict__ fc_b,
    float* __restrict__ out)
{
    __shared__ unsigned short lds[2][2][128 * 32];   // [buf][A/B][row*32+k], 32 KB

    const int bid = blockIdx.x;                      // 0..255
    const int swz = (bid & 7) * 32 + (bid >> 3);     // XCD swizzle (256%8==0)
    const int ct = swz & 7;                          // col tile (128 cols)
    const int rt = swz >> 3;                         // row tile (128 rows)
    const int row0 = rt * 128, col0 = ct * 128;

    const int t = threadIdx.x;
    const int w = t >> 6, lane = t & 63;
    const int n = lane & 15, quad = lane >> 4;
    const int wr = w >> 2, wc = w & 3;               // wave -> 64x32 sub-tile

    // A-staging: thread t covers row row0+(t>>2), k-chunk (t&3)*8 (16B)
    const int arow = row0 + (t >> 2);
    const unsigned short* pv  = vb  + (size_t)arow * DD + (t & 3) * 8;
    const unsigned short* pov = ovb + (size_t)arow * DD + (t & 3) * 8;
    const int scbase = (arow >> 11) * (HH * LL) + (arow & 2047);  // + h*LL
    // B-staging (gload_lds direct, linear)
    const unsigned short* gb = fcwb + (size_t)(col0 + (t >> 2)) * DD + (t & 3) * 8;
    unsigned short* la0 = &lds[0][0][t * 8];
    unsigned short* lb0 = &lds[0][1][t * 8];
    unsigned short* la1 = &lds[1][0][t * 8];
    unsigned short* lb1 = &lds[1][1][t * 8];
    const unsigned short* A0 = &lds[0][0][0];
    const unsigned short* B0 = &lds[0][1][0];
    const unsigned short* A1 = &lds[1][0][0];
    const unsigned short* B1 = &lds[1][1][0];

    f32x4 acc[4][2];
#pragma unroll
    for (int mt = 0; mt < 4; ++mt)
#pragma unroll
        for (int nt = 0; nt < 2; ++nt) acc[mt][nt] = (f32x4){0.f, 0.f, 0.f, 0.f};

    // prologue: A(0)->P, A(1)->Q, B(0)->lds0; write A(0)
    bf16x8 vP, ovP, vQ, ovQ; float zP, eP, csP, zQ, eQ, csQ;
    LOADA(vP, ovP, zP, eP, csP, 0);
    LOADA(vQ, ovQ, zQ, eQ, csQ, 1);
    gload16(gb, lb0);
    CVTWRITE(vP, ovP, zP, eP, csP, la0);
    __syncthreads();

    for (int kt = 0; kt < 32; kt += 2) {
        // even step: read lds0, prep lds1 with A(kt+1)/B(kt+1)
        gload16(gb + (kt + 1) * 32, lb1);
        if (kt + 2 < 32) LOADA(vP, ovP, zP, eP, csP, kt + 2);
        COMPUTE(A0, B0);
        CVTWRITE(vQ, ovQ, zQ, eQ, csQ, la1);
        __syncthreads();
        // odd step: read lds1, prep lds0 with A(kt+2)/B(kt+2)
        if (kt + 2 < 32) {
            gload16(gb + (kt + 2) * 32, lb0);
            if (kt + 3 < 32) LOADA(vQ, ovQ, zQ, eQ, csQ, kt + 3);
        }
        COMPUTE(A1, B1);
        if (kt + 2 < 32) CVTWRITE(vP, ovP, zP, eP, csP, la0);
        __syncthreads();
    }

#pragma unroll
    for (int nt = 0; nt < 2; ++nt) {
        const int col = col0 + wc * 32 + nt * 16 + n;
        const float bias = fc_b[col];
#pragma unroll
        for (int mt = 0; mt < 4; ++mt)
#pragma unroll
            for (int r = 0; r < 4; ++r)
                out[(size_t)(row0 + wr * 64 + mt * 16 + quad * 4 + r) * DD + col]
                    = acc[mt][nt][r] + bias;
    }
}

// ---------------------------------------------------------------------------
extern "C" void kernel_launch(void* const* d_in, const int* in_sizes, int n_in,
                              void* d_out, int out_size, void* d_ws, size_t ws_size,
                              hipStream_t stream) {
    const float* values = (const float*)d_in[0];
    const float* keys   = (const float*)d_in[1];
    const float* query  = (const float*)d_in[2];
    const float* ovals  = (const float*)d_in[3];
    const float* okeys  = (const float*)d_in[4];
    const float* Wv     = (const float*)d_in[5];
    const float* Wk     = (const float*)d_in[6];
    const float* Wq     = (const float*)d_in[7];
    const float* fc_w   = (const float*)d_in[8];
    const float* fc_b   = (const float*)d_in[9];
    // d_in[10]: mask — HIST==L makes it pure causal, handled analytically.
    float* out = (float*)d_out;

    float* ws      = (float*)d_ws;
    float* ediag   = ws;                     // 65536 f32
    float* Zbuf    = ediag + 65536;          // 65536 f32 (atomic accum)
    float* colsum  = Zbuf + 65536;           // 65536 f32 (atomic accum)
    unsigned short* qb   = (unsigned short*)(colsum + 65536); // [32][2048][64] bf16
    unsigned short* okb  = qb   + 4194304;
    unsigned short* vb   = okb  + 4194304;   // [n][l][1024] bf16
    unsigned short* ovb  = vb   + 4194304;
    unsigned short* fcwb = ovb  + 4194304;   // [1024][1024] bf16
    unsigned short* wfrag = fcwb + 1048576;  // 3*8*64*8 = 12288 bf16 (24 KB)

    // prep: wcvt + fcw + zero(Zbuf,colsum) in one launch
    prep_kernel<<<dim3(1158), 256, 0, stream>>>(Wk, Wq, Wv, wfrag, fc_w, fcwb, Zbuf);
    proj_kernel<<<dim3(64, 16, 2), 256, 0, stream>>>(
        values, keys, query, ovals, okeys, wfrag, qb, okb, vb, ovb, ediag);
    zrow_part<<<dim3(1024), 256, 0, stream>>>(qb, okb, Zbuf);
    colsum_part<<<dim3(1024), 256, 0, stream>>>(qb, okb, Zbuf, ediag, colsum);
    out_kernel<<<dim3(256), 512, 0, stream>>>(vb, ovb, Zbuf, ediag, colsum, fcwb, fc_b, out);
}

// Round 6
// 222.626 us; speedup vs baseline: 1.1107x; 1.1107x over previous
//
#include <hip/hip_runtime.h>

// Problem constants
#define NB 2
#define LL 2048
#define DD 1024
#define HH 16
#define NHH (NB*HH)          // 32 (n,h) pairs
#define LT (LL/64)           // 32 tiles of 64
#define KT16 (LL/16)         // 128 16-col tiles
#define CEXP 0.0450842200277801f   // log2(e)/32 : exp(x/32) == exp2(x*CEXP)

typedef __bf16 bf16x8 __attribute__((ext_vector_type(8)));
typedef unsigned short u16x8 __attribute__((ext_vector_type(8)));
typedef float f32x4 __attribute__((ext_vector_type(4)));

#define MFMA16 __builtin_amdgcn_mfma_f32_16x16x32_bf16
#define EXP2 __builtin_amdgcn_exp2f

__device__ __forceinline__ unsigned short f2bf(float f) {
    unsigned u = __float_as_uint(f);
    return (unsigned short)((u + 0x7fffu + ((u >> 16) & 1u)) >> 16);   // RNE
}
__device__ __forceinline__ float bf2f(unsigned short u) {
    return __uint_as_float(((unsigned)u) << 16);
}
__device__ __forceinline__ bf16x8 ldfrag(const unsigned short* p) {
    return *reinterpret_cast<const bf16x8*>(p);
}
__device__ __forceinline__ bf16x8 cvt8v(float4 a, float4 b) {
    u16x8 u;
    u[0]=f2bf(a.x); u[1]=f2bf(a.y); u[2]=f2bf(a.z); u[3]=f2bf(a.w);
    u[4]=f2bf(b.x); u[5]=f2bf(b.y); u[6]=f2bf(b.z); u[7]=f2bf(b.w);
    return __builtin_bit_cast(bf16x8, u);
}
__device__ __forceinline__ ushort4 pack4(f32x4 d, float sc) {
    ushort4 o;
    o.x = f2bf(d[0]*sc); o.y = f2bf(d[1]*sc); o.z = f2bf(d[2]*sc); o.w = f2bf(d[3]*sc);
    return o;
}
// async global->LDS, 16B per lane; LDS dest must be linear (base + lane*16)
__device__ __forceinline__ void gload16(const unsigned short* g, unsigned short* l) {
    __builtin_amdgcn_global_load_lds(
        (const __attribute__((address_space(1))) unsigned int*)g,
        (__attribute__((address_space(3))) unsigned int*)l, 16, 0, 0);
}

// ---------------------------------------------------------------------------
// K0 (prep): merged wcvt (6 blocks) + fcw cvt (1024 blocks). The atomic-
// accumulator zeroing is GONE: zrow/colsum now write their outputs with
// plain stores (single-owner blocks), no atomics.
// ---------------------------------------------------------------------------
__global__ __launch_bounds__(256) void prep_kernel(
    const float* __restrict__ Wk, const float* __restrict__ Wq,
    const float* __restrict__ Wv, unsigned short* __restrict__ wfrag,
    const float* __restrict__ fc_w, unsigned short* __restrict__ fcwb)
{
    const int bid = blockIdx.x;
    const int t = threadIdx.x;
    if (bid < 6) {
        // wcvt: Wk,Wq,Wv -> bf16 MFMA A-frags, proj's per-lane layout
        const int s = bid * 256 + t;   // 0..1535
        const int m = s >> 9;
        const int rem = s & 511;
        const int f = rem >> 6;
        const int lane = rem & 63;
        const int n16 = lane & 15, quad = lane >> 4;
        const int mt = f >> 1, half = f & 1;
        const float* W = (m == 0) ? Wk : (m == 1) ? Wq : Wv;
        const float* p = W + (mt*16 + n16)*64 + quad*8 + half*32;
        float4 a = *reinterpret_cast<const float4*>(p);
        float4 b = *reinterpret_cast<const float4*>(p + 4);
        *reinterpret_cast<bf16x8*>(wfrag + (size_t)s * 8) = cvt8v(a, b);
    } else {
        // fcw: fc_w fp32 -> bf16
        const int idx = (bid - 6) * 1024 + t * 4;
        float4 wv = *reinterpret_cast<const float4*>(fc_w + idx);
        ushort4 o;
        o.x = f2bf(wv.x); o.y = f2bf(wv.y); o.z = f2bf(wv.z); o.w = f2bf(wv.w);
        *reinterpret_cast<ushort4*>(fcwb + idx) = o;
    }
}

// ---------------------------------------------------------------------------
// K1: projections via MFMA, D = W(A) . X^T(B); grid (64,16,2).
// z=0: keys/query/okeys (Wk,Wq) + ediag; z=1: values/ovals (Wv).
// ---------------------------------------------------------------------------
__global__ __launch_bounds__(256) void proj_kernel(
    const float* __restrict__ values, const float* __restrict__ keys,
    const float* __restrict__ query,  const float* __restrict__ ovals,
    const float* __restrict__ okeys,  const unsigned short* __restrict__ wfrag,
    unsigned short* __restrict__ qb, unsigned short* __restrict__ okb,
    unsigned short* __restrict__ vb, unsigned short* __restrict__ ovb,
    float* __restrict__ ediag)
{
    const int t = threadIdx.x;
    const int w = t >> 6;
    const int lane = t & 63;
    const int n16 = lane & 15;
    const int quad = lane >> 4;
    const int h = blockIdx.y;
    const int row = blockIdx.x * 64 + w * 16 + n16;  // (n*L+l) == this lane's C-col
    const int nn = row >> 11;
    const int ll = row & 2047;
    const size_t xoff  = (size_t)row * DD + h * 64 + quad * 8;       // B-frag src
    const size_t qbase = (((size_t)(nn * HH + h)) * LL + ll) * 64;   // [nh][l][64]
    const size_t vbase = (size_t)row * DD + h * 64;                  // [row][1024]

    if (blockIdx.z == 0) {
        // ---- issue ALL loads first (independent) ----
        const float4* kp = reinterpret_cast<const float4*>(keys  + xoff);
        const float4* qp = reinterpret_cast<const float4*>(query + xoff);
        const float4* op = reinterpret_cast<const float4*>(okeys + xoff);
        float4 k0 = kp[0], k1 = kp[1], k2 = kp[8], k3 = kp[9];   // +0,+4,+32,+36
        float4 q0 = qp[0], q1 = qp[1], q2 = qp[8], q3 = qp[9];
        float4 o0 = op[0], o1 = op[1], o2 = op[8], o3 = op[9];
        bf16x8 wk[8], wq[8];
#pragma unroll
        for (int f = 0; f < 8; ++f) {
            wk[f] = ldfrag(wfrag + (size_t)(f * 64 + lane) * 8);
            wq[f] = ldfrag(wfrag + (size_t)((8 + f) * 64 + lane) * 8);
        }
        // ---- convert ----
        bf16x8 xk0 = cvt8v(k0, k1), xk1 = cvt8v(k2, k3);
        bf16x8 xq0 = cvt8v(q0, q1), xq1 = cvt8v(q2, q3);
        bf16x8 xo0 = cvt8v(o0, o1), xo1 = cvt8v(o2, o3);
        // ---- MFMA ----
        f32x4 ka[4], qa[4];
#pragma unroll
        for (int mt = 0; mt < 4; ++mt) {
            f32x4 d = {0.f,0.f,0.f,0.f};
            d = MFMA16(wk[mt*2], xk0, d, 0,0,0);
            ka[mt] = MFMA16(wk[mt*2+1], xk1, d, 0,0,0);
        }
#pragma unroll
        for (int mt = 0; mt < 4; ++mt) {
            f32x4 d = {0.f,0.f,0.f,0.f};
            d = MFMA16(wq[mt*2], xq0, d, 0,0,0);
            qa[mt] = MFMA16(wq[mt*2+1], xq1, d, 0,0,0);
            *reinterpret_cast<ushort4*>(qb + qbase + mt*16 + quad*4) = pack4(qa[mt], CEXP);
        }
#pragma unroll
        for (int mt = 0; mt < 4; ++mt) {
            f32x4 d = {0.f,0.f,0.f,0.f};
            d = MFMA16(wk[mt*2], xo0, d, 0,0,0);
            d = MFMA16(wk[mt*2+1], xo1, d, 0,0,0);
            *reinterpret_cast<ushort4*>(okb + qbase + mt*16 + quad*4) = pack4(d, 1.0f);
        }
        // ediag[l] = sum_d q*k (fp32)
        float p = 0.f;
#pragma unroll
        for (int mt = 0; mt < 4; ++mt)
            p += qa[mt][0]*ka[mt][0] + qa[mt][1]*ka[mt][1]
               + qa[mt][2]*ka[mt][2] + qa[mt][3]*ka[mt][3];
        p += __shfl_xor(p, 16);
        p += __shfl_xor(p, 32);
        if (lane < 16)
            ediag[((size_t)(nn * HH + h)) * LL + ll] = p;
    } else {
        const float4* vp = reinterpret_cast<const float4*>(values + xoff);
        const float4* op = reinterpret_cast<const float4*>(ovals  + xoff);
        float4 v0 = vp[0], v1 = vp[1], v2 = vp[8], v3 = vp[9];
        float4 o0 = op[0], o1 = op[1], o2 = op[8], o3 = op[9];
        bf16x8 wv[8];
#pragma unroll
        for (int f = 0; f < 8; ++f)
            wv[f] = ldfrag(wfrag + (size_t)((16 + f) * 64 + lane) * 8);
        bf16x8 xv0 = cvt8v(v0, v1), xv1 = cvt8v(v2, v3);
        bf16x8 xo0 = cvt8v(o0, o1), xo1 = cvt8v(o2, o3);
#pragma unroll
        for (int mt = 0; mt < 4; ++mt) {
            f32x4 d = {0.f,0.f,0.f,0.f};
            d = MFMA16(wv[mt*2], xv0, d, 0,0,0);
            d = MFMA16(wv[mt*2+1], xv1, d, 0,0,0);
            *reinterpret_cast<ushort4*>(vb + vbase + mt*16 + quad*4) = pack4(d, 1.0f);
        }
#pragma unroll
        for (int mt = 0; mt < 4; ++mt) {
            f32x4 d = {0.f,0.f,0.f,0.f};
            d = MFMA16(wv[mt*2], xo0, d, 0,0,0);
            d = MFMA16(wv[mt*2+1], xo1, d, 0,0,0);
            *reinterpret_cast<ushort4*>(ovb + vbase + mt*16 + quad*4) = pack4(d, 1.0f);
        }
    }
}

// ---------------------------------------------------------------------------
// K2: Z[q] = sum_{l<q} exp(e[q,l]/32), restructured as an LDS-staged
// mini-GEMM (R4 post-mortem: old per-wave streamed-frag form was structure-
// bound -- rotation movs, redundant frag loads, atomics; 4x traffic cut gave
// 0 speedup). One block per (nh, qt 64-q tile); wave w owns q-subtile w
// (B-frags from qb, held in regs). okb l-strips (64x64) staged ONCE per
// block into double-buffered LDS via pre-swizzled-source global_load_lds
// (chunk ^= row&7 -> conflict-free ds_read_b128). One barrier per strip.
// Output: plain store (single owner), no atomics. Long blocks (qt=31) first.
// ---------------------------------------------------------------------------
__global__ __launch_bounds__(256) void zrow_part(
    const unsigned short* __restrict__ qb, const unsigned short* __restrict__ okb,
    float* __restrict__ Zbuf)
{
    __shared__ unsigned short slds[2][64 * 64];   // 2 x 8KB staged okb strips

    const int bid = blockIdx.x;       // 0..1023
    const int nh = bid & 31;
    const int qt = 31 - (bid >> 5);   // longest (32 strips) first
    const int t = threadIdx.x;
    const int w = t >> 6;
    const int lane = t & 63;
    const int n = lane & 15;
    const int quad = lane >> 4;
    const size_t base = (size_t)nh * (LL * 64);
    const size_t nhL = (size_t)nh * LL;

    // held B-frags: qb rows q = qt*64 + w*16 + n
    const unsigned short* bp = qb + base + (size_t)(qt*64 + w*16 + n) * 64 + quad * 8;
    const bf16x8 bq0 = ldfrag(bp);
    const bf16x8 bq1 = ldfrag(bp + 32);

    // staging: thread t -> strip-rows srow, srow+32; source chunk pre-swizzled
    const int srow = t >> 3;                        // 0..31
    const int schunk = (t & 7) ^ (srow & 7);        // inverse of read swizzle
    const int soff = srow * 64 + schunk * 8;
    const int nst = qt + 1;

    {   // prologue: stage strip 0 (l in [0,64))
        const unsigned short* s0 = okb + base + soff;
        gload16(s0, &slds[0][t * 8]);
        gload16(s0 + 32 * 64, &slds[0][2048 + t * 8]);
    }
    __syncthreads();

    const int rs0 = (quad ^ (n & 7)) * 8;           // swizzled read offsets
    const int rs1 = ((quad + 4) ^ (n & 7)) * 8;

    float zacc = 0.f;
    int buf = 0;
    for (int si = 0; si < nst; ++si) {
        if (si + 1 < nst) {                         // stage next strip first
            const unsigned short* s0 = okb + base + (size_t)((si + 1) * 64) * 64 + soff;
            gload16(s0, &slds[buf ^ 1][t * 8]);
            gload16(s0 + 32 * 64, &slds[buf ^ 1][2048 + t * 8]);
        }
        const unsigned short* S = &slds[buf][0];
        const bool dstrip = (si == qt);             // strip containing l == q
#pragma unroll
        for (int sub = 0; sub < 4; ++sub) {
            if (dstrip && sub > w) continue;        // l > q entirely
            const int row = sub * 16 + n;
            const bf16x8 a0 = ldfrag(S + row * 64 + rs0);
            const bf16x8 a1 = ldfrag(S + row * 64 + rs1);
            f32x4 d = {0.f, 0.f, 0.f, 0.f};
            d = MFMA16(a0, bq0, d, 0, 0, 0);
            d = MFMA16(a1, bq1, d, 0, 0, 0);
            if (dstrip && sub == w) {               // diagonal: keep l < q
#pragma unroll
                for (int r = 0; r < 4; ++r)
                    if (quad * 4 + r < n) zacc += EXP2(d[r]);
            } else {
#pragma unroll
                for (int r = 0; r < 4; ++r) zacc += EXP2(d[r]);
            }
        }
        __syncthreads();                            // next buf staged; reads done
        buf ^= 1;
    }

    zacc += __shfl_down(zacc, 32);
    zacc += __shfl_down(zacc, 16);
    if (lane < 16)
        Zbuf[nhL + qt * 64 + w * 16 + lane] = zacc;   // plain store, single owner
}

// ---------------------------------------------------------------------------
// K3: colsum[l] = sum_{q>l} exp(e[q,l]/32) / Z_full[q], same LDS-staged
// structure: block owns (nh, lt 64-l tile); wave w holds okb l-subtile w;
// qb q-strips staged in LDS; iz[64] computed cooperatively (wave 0) per
// strip into LDS -- kills the per-wave-redundant exp2/rcp of the old form.
// ---------------------------------------------------------------------------
__global__ __launch_bounds__(256) void colsum_part(
    const unsigned short* __restrict__ qb, const unsigned short* __restrict__ okb,
    const float* __restrict__ Zbuf, const float* __restrict__ ediag,
    float* __restrict__ colsum)
{
    __shared__ unsigned short slds[2][64 * 64];   // 2 x 8KB staged qb strips
    __shared__ __align__(16) float izlds[2][64];

    const int bid = blockIdx.x;       // 0..1023
    const int nh = bid & 31;
    const int lt = bid >> 5;          // lt=0 (32 strips) first
    const int t = threadIdx.x;
    const int w = t >> 6;
    const int lane = t & 63;
    const int n = lane & 15;
    const int quad = lane >> 4;
    const size_t base = (size_t)nh * (LL * 64);
    const size_t nhL = (size_t)nh * LL;

    // held B-frags: okb rows l = lt*64 + w*16 + n
    const unsigned short* bp = okb + base + (size_t)(lt*64 + w*16 + n) * 64 + quad * 8;
    const bf16x8 bl0 = ldfrag(bp);
    const bf16x8 bl1 = ldfrag(bp + 32);

    const int srow = t >> 3;
    const int schunk = (t & 7) ^ (srow & 7);
    const int soff = srow * 64 + schunk * 8;
    const int nst = 32 - lt;
    const int q00 = lt * 64;                        // strip si q-base = q00+si*64

    {   // prologue: stage strip 0 + its iz
        const unsigned short* s0 = qb + base + (size_t)q00 * 64 + soff;
        gload16(s0, &slds[0][t * 8]);
        gload16(s0 + 32 * 64, &slds[0][2048 + t * 8]);
        if (t < 64) {
            const float z = Zbuf[nhL + q00 + t];
            const float e = ediag[nhL + q00 + t];
            izlds[0][t] = 1.f / (z + EXP2(e * CEXP));
        }
    }
    __syncthreads();

    const int rs0 = (quad ^ (n & 7)) * 8;
    const int rs1 = ((quad + 4) ^ (n & 7)) * 8;

    float cacc = 0.f;
    int buf = 0;
    for (int si = 0; si < nst; ++si) {
        if (si + 1 < nst) {
            const int qn = q00 + (si + 1) * 64;
            const unsigned short* s0 = qb + base + (size_t)qn * 64 + soff;
            gload16(s0, &slds[buf ^ 1][t * 8]);
            gload16(s0 + 32 * 64, &slds[buf ^ 1][2048 + t * 8]);
            if (t < 64) {
                const float z = Zbuf[nhL + qn + t];
                const float e = ediag[nhL + qn + t];
                izlds[buf ^ 1][t] = 1.f / (z + EXP2(e * CEXP));
            }
        }
        const unsigned short* S = &slds[buf][0];
        const bool dstrip = (si == 0);              // strip containing q == l
#pragma unroll
        for (int sub = 0; sub < 4; ++sub) {
            if (dstrip && sub < w) continue;        // q < l entirely
            const int row = sub * 16 + n;
            const bf16x8 a0 = ldfrag(S + row * 64 + rs0);
            const bf16x8 a1 = ldfrag(S + row * 64 + rs1);
            const f32x4 izv = *reinterpret_cast<const f32x4*>(&izlds[buf][sub * 16 + quad * 4]);
            f32x4 d = {0.f, 0.f, 0.f, 0.f};
            d = MFMA16(a0, bl0, d, 0, 0, 0);
            d = MFMA16(a1, bl1, d, 0, 0, 0);
            if (dstrip && sub == w) {               // diagonal: keep q > l
#pragma unroll
                for (int r = 0; r < 4; ++r)
                    if (quad * 4 + r > n) cacc += EXP2(d[r]) * izv[r];
            } else {
#pragma unroll
                for (int r = 0; r < 4; ++r) cacc += EXP2(d[r]) * izv[r];
            }
        }
        __syncthreads();
        buf ^= 1;
    }

    cacc += __shfl_down(cacc, 32);
    cacc += __shfl_down(cacc, 16);
    if (lane < 16)
        colsum[nhL + lt * 64 + w * 16 + lane] = cacc;  // plain store
}

// ---------------------------------------------------------------------------
// K6: out = (diag_s*vb + colsum*ovb) @ fcwb^T + fc_b  -- att fused into the
// GEMM's A-staging; diag_s computed inline from Zbuf+ediag.
// ---------------------------------------------------------------------------
#define LOADA(vS, ovS, zS, eS, csS, k) do {                                \
    vS  = ldfrag(pv  + (k)*32);                                            \
    ovS = ldfrag(pov + (k)*32);                                            \
    zS  = Zbuf  [scbase + ((k)>>1)*LL];                                    \
    eS  = ediag [scbase + ((k)>>1)*LL];                                    \
    csS = colsum[scbase + ((k)>>1)*LL];                                    \
} while (0)

#define CVTWRITE(vS, ovS, zS, eS, csS, dst) do {                           \
    const float de_ = EXP2(eS * CEXP);                                     \
    const float ds_ = de_ * (1.f / (zS + de_));                            \
    u16x8 vu_ = __builtin_bit_cast(u16x8, vS);                             \
    u16x8 ou_ = __builtin_bit_cast(u16x8, ovS);                            \
    u16x8 o_;                                                              \
    _Pragma("unroll")                                                      \
    for (int i_ = 0; i_ < 8; ++i_)                                         \
        o_[i_] = f2bf(ds_ * bf2f(vu_[i_]) + csS * bf2f(ou_[i_]));          \
    *reinterpret_cast<u16x8*>(dst) = o_;                                   \
} while (0)

#define COMPUTE(Abuf, Bbuf) do {                                           \
    bf16x8 af_[4], bf_[2];                                                 \
    _Pragma("unroll")                                                      \
    for (int mt = 0; mt < 4; ++mt)                                         \
        af_[mt] = ldfrag((Abuf) + (wr*64 + mt*16 + n)*32 + quad*8);        \
    _Pragma("unroll")                                                      \
    for (int nt = 0; nt < 2; ++nt)                                         \
        bf_[nt] = ldfrag((Bbuf) + (wc*32 + nt*16 + n)*32 + quad*8);        \
    _Pragma("unroll")                                                      \
    for (int mt = 0; mt < 4; ++mt)                                         \
        _Pragma("unroll")                                                  \
        for (int nt = 0; nt < 2; ++nt)                                     \
            acc[mt][nt] = MFMA16(af_[mt], bf_[nt], acc[mt][nt], 0,0,0);    \
} while (0)

__global__ __launch_bounds__(512) void out_kernel(
    const unsigned short* __restrict__ vb, const unsigned short* __restrict__ ovb,
    const float* __restrict__ Zbuf, const float* __restrict__ ediag,
    const float* __restrict__ colsum,
    const unsigned short* __restrict__ fcwb, const float* __restrict__ fc_b,
    float* __restrict__ out)
{
    __shared__ unsigned short lds[2][2][128 * 32];   // [buf][A/B][row*32+k], 32 KB

    const int bid = blockIdx.x;                      // 0..255
    const int swz = (bid & 7) * 32 + (bid >> 3);     // XCD swizzle (256%8==0)
    const int ct = swz & 7;                          // col tile (128 cols)
    const int rt = swz >> 3;                         // row tile (128 rows)
    const int row0 = rt * 128, col0 = ct * 128;

    const int t = threadIdx.x;
    const int w = t >> 6, lane = t & 63;
    const int n = lane & 15, quad = lane >> 4;
    const int wr = w >> 2, wc = w & 3;               // wave -> 64x32 sub-tile

    // A-staging: thread t covers row row0+(t>>2), k-chunk (t&3)*8 (16B)
    const int arow = row0 + (t >> 2);
    const unsigned short* pv  = vb  + (size_t)arow * DD + (t & 3) * 8;
    const unsigned short* pov = ovb + (size_t)arow * DD + (t & 3) * 8;
    const int scbase = (arow >> 11) * (HH * LL) + (arow & 2047);  // + h*LL
    // B-staging (gload_lds direct, linear)
    const unsigned short* gb = fcwb + (size_t)(col0 + (t >> 2)) * DD + (t & 3) * 8;
    unsigned short* la0 = &lds[0][0][t * 8];
    unsigned short* lb0 = &lds[0][1][t * 8];
    unsigned short* la1 = &lds[1][0][t * 8];
    unsigned short* lb1 = &lds[1][1][t * 8];
    const unsigned short* A0 = &lds[0][0][0];
    const unsigned short* B0 = &lds[0][1][0];
    const unsigned short* A1 = &lds[1][0][0];
    const unsigned short* B1 = &lds[1][1][0];

    f32x4 acc[4][2];
#pragma unroll
    for (int mt = 0; mt < 4; ++mt)
#pragma unroll
        for (int nt = 0; nt < 2; ++nt) acc[mt][nt] = (f32x4){0.f, 0.f, 0.f, 0.f};

    // prologue: A(0)->P, A(1)->Q, B(0)->lds0; write A(0)
    bf16x8 vP, ovP, vQ, ovQ; float zP, eP, csP, zQ, eQ, csQ;
    LOADA(vP, ovP, zP, eP, csP, 0);
    LOADA(vQ, ovQ, zQ, eQ, csQ, 1);
    gload16(gb, lb0);
    CVTWRITE(vP, ovP, zP, eP, csP, la0);
    __syncthreads();

    for (int kt = 0; kt < 32; kt += 2) {
        // even step: read lds0, prep lds1 with A(kt+1)/B(kt+1)
        gload16(gb + (kt + 1) * 32, lb1);
        if (kt + 2 < 32) LOADA(vP, ovP, zP, eP, csP, kt + 2);
        COMPUTE(A0, B0);
        CVTWRITE(vQ, ovQ, zQ, eQ, csQ, la1);
        __syncthreads();
        // odd step: read lds1, prep lds0 with A(kt+2)/B(kt+2)
        if (kt + 2 < 32) {
            gload16(gb + (kt + 2) * 32, lb0);
            if (kt + 3 < 32) LOADA(vQ, ovQ, zQ, eQ, csQ, kt + 3);
        }
        COMPUTE(A1, B1);
        if (kt + 2 < 32) CVTWRITE(vP, ovP, zP, eP, csP, la0);
        __syncthreads();
    }

#pragma unroll
    for (int nt = 0; nt < 2; ++nt) {
        const int col = col0 + wc * 32 + nt * 16 + n;
        const float bias = fc_b[col];
#pragma unroll
        for (int mt = 0; mt < 4; ++mt)
#pragma unroll
            for (int r = 0; r < 4; ++r)
                out[(size_t)(row0 + wr * 64 + mt * 16 + quad * 4 + r) * DD + col]
                    = acc[mt][nt][r] + bias;
    }
}

// ---------------------------------------------------------------------------
extern "C" void kernel_launch(void* const* d_in, const int* in_sizes, int n_in,
                              void* d_out, int out_size, void* d_ws, size_t ws_size,
                              hipStream_t stream) {
    const float* values = (const float*)d_in[0];
    const float* keys   = (const float*)d_in[1];
    const float* query  = (const float*)d_in[2];
    const float* ovals  = (const float*)d_in[3];
    const float* okeys  = (const float*)d_in[4];
    const float* Wv     = (const float*)d_in[5];
    const float* Wk     = (const float*)d_in[6];
    const float* Wq     = (const float*)d_in[7];
    const float* fc_w   = (const float*)d_in[8];
    const float* fc_b   = (const float*)d_in[9];
    // d_in[10]: mask — HIST==L makes it pure causal, handled analytically.
    float* out = (float*)d_out;

    float* ws      = (float*)d_ws;
    float* ediag   = ws;                     // 65536 f32
    float* Zbuf    = ediag + 65536;          // 65536 f32 (plain stores now)
    float* colsum  = Zbuf + 65536;           // 65536 f32 (plain stores now)
    unsigned short* qb   = (unsigned short*)(colsum + 65536); // [32][2048][64] bf16
    unsigned short* okb  = qb   + 4194304;
    unsigned short* vb   = okb  + 4194304;   // [n][l][1024] bf16
    unsigned short* ovb  = vb   + 4194304;
    unsigned short* fcwb = ovb  + 4194304;   // [1024][1024] bf16
    unsigned short* wfrag = fcwb + 1048576;  // 3*8*64*8 = 12288 bf16 (24 KB)

    prep_kernel<<<dim3(1030), 256, 0, stream>>>(Wk, Wq, Wv, wfrag, fc_w, fcwb);
    proj_kernel<<<dim3(64, 16, 2), 256, 0, stream>>>(
        values, keys, query, ovals, okeys, wfrag, qb, okb, vb, ovb, ediag);
    zrow_part<<<dim3(1024), 256, 0, stream>>>(qb, okb, Zbuf);
    colsum_part<<<dim3(1024), 256, 0, stream>>>(qb, okb, Zbuf, ediag, colsum);
    out_kernel<<<dim3(256), 512, 0, stream>>>(vb, ovb, Zbuf, ediag, colsum, fcwb, fc_b, out);
}